// Round 12
// baseline (219.041 us; speedup 1.0000x reference)
//
#include <hip/hip_runtime.h>
#include <stdint.h>

typedef __attribute__((ext_vector_type(8))) short short8;
typedef __attribute__((ext_vector_type(4))) float f32x4;
typedef __attribute__((ext_vector_type(4))) unsigned int u32x4;
typedef __attribute__((ext_vector_type(2))) unsigned int u32x2;

#define MFMA16(a, b, c) __builtin_amdgcn_mfma_f32_16x16x32_bf16((a), (b), (c), 0, 0, 0)

// async global->LDS DMA, 16B per lane; LDS dest = wave-uniform base + lane*16
#define GLD_LDS16(g, l)                                                                  \
    __builtin_amdgcn_global_load_lds((const __attribute__((address_space(1))) void*)(g), \
                                     (__attribute__((address_space(3))) void*)(l), 16, 0, 0)

// single-instruction v_exp_f32 (exp2f without -ffast-math is a slow libm call)
#if defined(__has_builtin)
#if __has_builtin(__builtin_amdgcn_exp2f)
#define FAST_EXP2(x) __builtin_amdgcn_exp2f(x)
#endif
#endif
#ifndef FAST_EXP2
__device__ __forceinline__ float fast_exp2_asm(float x) {
    float r;
    asm volatile("v_exp_f32 %0, %1\ns_nop 1" : "=v"(r) : "v"(x));
    return r;
}
#define FAST_EXP2(x) fast_exp2_asm(x)
#endif

#if defined(__has_builtin)
#if __has_builtin(__builtin_amdgcn_permlane32_swap) && __has_builtin(__builtin_amdgcn_permlane16_swap)
#define HAVE_PERMLANE_SWAP 1
#endif
#endif

// Regroup a pair of packed-u32 registers across quads:
//   in : x = [X0,X1,X2,X3], y = [Y0,Y1,Y2,Y3]   (quad-rows of 16 lanes)
//   out: x = [X0,X2,Y0,Y2], y = [X1,X3,Y1,Y3]
// via permlane32_swap then permlane16_swap. Builtin path lets the compiler insert
// the cross-lane hazard wait-states (raw asm was the round-4 nondeterminism bug);
// fallback asm carries generous s_nop padding for the same reason.
__device__ __forceinline__ void permlane_regroup(unsigned int& x, unsigned int& y) {
#ifdef HAVE_PERMLANE_SWAP
    {
        auto r = __builtin_amdgcn_permlane32_swap(x, y, false, false);
        auto r2 = __builtin_amdgcn_permlane16_swap(r[0], r[1], false, false);
        x = r2[0];
        y = r2[1];
    }
#else
    asm volatile(
        "s_nop 3\n\t"
        "v_permlane32_swap_b32 %0, %1\n\t"
        "s_nop 3\n\t"
        "v_permlane16_swap_b32 %0, %1\n\t"
        "s_nop 3"
        : "+v"(x), "+v"(y));
#endif
}

__device__ __forceinline__ float bf2f(unsigned short u) {
    unsigned int x = ((unsigned int)u) << 16;
    float f;
    __builtin_memcpy(&f, &x, 4);
    return f;
}
__device__ __forceinline__ unsigned short f2bf(float f) {  // RNE
    unsigned int x;
    __builtin_memcpy(&x, &f, 4);
    unsigned int r = x + 0x7FFFu + ((x >> 16) & 1u);
    return (unsigned short)(r >> 16);
}
// pack two f32 -> two bf16 (round-half-up) in one u32
__device__ __forceinline__ unsigned int pack2bf(float a, float b) {
    unsigned int ua, ub;
    __builtin_memcpy(&ua, &a, 4);
    __builtin_memcpy(&ub, &b, 4);
    return __builtin_amdgcn_perm(ub + 0x8000u, ua + 0x8000u, 0x07060302u);
}
// single-instruction pack: lo = bf16(a), hi = bf16(b), RNE.
// Trailing s_nop covers the VALU-write -> cross-lane-read hazard when the result
// feeds a permlane (compiler cannot see inside this asm to insert wait-states).
__device__ __forceinline__ unsigned int cvtpk_bf16(float a, float b) {
    unsigned int r;
    asm("v_cvt_pk_bf16_f32 %0, %1, %2\n\ts_nop 1" : "=v"(r) : "v"(a), "v"(b));
    return r;
}
// no-s_nop variant: result feeds MEMORY (ds_write), not a cross-lane op
__device__ __forceinline__ unsigned int cvtpk_bf16_ns(float a, float b) {
    unsigned int r;
    asm("v_cvt_pk_bf16_f32 %0, %1, %2" : "=v"(r) : "v"(a), "v"(b));
    return r;
}
__device__ __forceinline__ u32x4 cvt8(const float* p) {
    f32x4 g0 = *(const f32x4*)p;
    f32x4 g1 = *(const f32x4*)(p + 4);
    u32x4 r;
    r.x = pack2bf(g0[0], g0[1]);
    r.y = pack2bf(g0[2], g0[3]);
    r.z = pack2bf(g1[0], g1[1]);
    r.w = pack2bf(g1[2], g1[3]);
    return r;
}

// elementwise f32 -> bf16 for the two weight matrices (x is now fused into GEMM0)
__global__ __launch_bounds__(256) void cvt2_kernel(const float* __restrict__ a,
                                                   unsigned short* __restrict__ oa,
                                                   const float* __restrict__ b,
                                                   unsigned short* __restrict__ ob, int n8) {
    int i = blockIdx.x * 256 + threadIdx.x;
    if (i < n8) {
        *(u32x4*)(oa + (size_t)i * 8) = cvt8(a + (size_t)i * 8);
    } else if (i < 2 * n8) {
        int j = i - n8;
        *(u32x4*)(ob + (size_t)j * 8) = cvt8(b + (size_t)j * 8);
    }
}

// ---------- main-path GEMM: BM=BN=128, BK=64, 8 waves, conflict-free LDS ----------
// C = A @ B^T + bias; B [N,K] bf16 (weight [out,in]).
// AF32=1: A is f32 (x) — REG-STAGED with inline f32->bf16 convert (kills the
//   separate 32MB cvt pass): loads issued right after the barrier (latency hides
//   under the MFMA phase, T14 split), converted + ds_written SWIZZLED after MFMAs
//   (reg-staging has no DMA dest constraint, so the write applies the XOR itself).
//   ds_write bank check: an 8-lane phase covers slots {0,2,4,6}^e u {0,2,4,6}^(e^1)
//   = all 8 distinct 16B slots -> conflict-free.
// AF32=0: A is bf16 — proven global_load_lds DMA path (r11).
// B always bf16 via DMA. LDS [128][64] 128B rows, XOR-16B-slot swizzle (slot^=row&7),
// linear DMA dest + pre-swizzled global source (rule 21/m173).
// MODE 0: C bf16 scattered head-major V; MODE 1: C f32 row-major.
template <bool AF32, int MODE>
__global__ __launch_bounds__(512, 4) void gemm_dma_kernel(
    const void* __restrict__ Av, const unsigned short* __restrict__ B,
    const float* __restrict__ bias, void* __restrict__ Cv, int M, int N, int K) {
    __shared__ __align__(16) unsigned short As[2][128 * 64];  // [stage][row][64], swizzled
    __shared__ __align__(16) unsigned short Bs[2][128 * 64];

    const int tid = threadIdx.x;
    const int wave = tid >> 6, lane = tid & 63;  // wave 0..7
    const int l15 = lane & 15, quad = lane >> 4;
    const int sx = l15 & 7;  // row&7 for fragment rows (row = base16*k + l15)
    // XCD remap: id round-robins XCDs; each XCD owns 8 contiguous m-tiles, n fastest.
    const int id = blockIdx.y * gridDim.x + blockIdx.x;  // dispatch-linear
    const int xcd = id & 7;
    const int p = id >> 3;
    const int m0 = (xcd * 8 + (p >> 3)) * 128, n0 = (p & 7) * 128;
    const int wm = (wave >> 2) * 64, wn = (wave & 3) * 32;  // 2x4 wave grid, 64x32 each

    // DMA source geometry (B always; A when bf16): wave stages 16 rows (2 instrs x 8
    // rows of 128B); lane row-within-instr = lane>>3, col slot (lane&7)^(lane>>3).
    const int srow = wave * 16 + (lane >> 3);
    const int scol = ((lane & 7) ^ (lane >> 3)) * 8;
    const unsigned short* Bg = B + (size_t)(n0 + srow) * K + scol;
    const int wl = wave * 1024;  // 16 rows x 64 shorts; lane*16B appended by HW

    // A reg-staged geometry (AF32): lane covers row arow, 16 f32 cols from acol.
    const int arow = wave * 16 + (lane >> 2);
    const int acol = (lane & 3) * 16;
    const float* Agf = AF32 ? (const float*)Av + (size_t)(m0 + arow) * K + acol : nullptr;
    const unsigned short* Agb =
        AF32 ? nullptr : (const unsigned short*)Av + (size_t)(m0 + srow) * K + scol;
    const int wbase = arow * 64;
    const int wslot0 = ((((lane & 3) * 2) ^ (arow & 7)) << 3);
    const int wslot1 = ((((lane & 3) * 2 + 1) ^ (arow & 7)) << 3);

#define BSTAGE(s, k0)                                   \
    do {                                                \
        GLD_LDS16(Bg + (k0), &Bs[s][wl]);               \
        GLD_LDS16(Bg + (k0) + 8 * K, &Bs[s][wl + 512]); \
    } while (0)
#define ASTAGE_DMA(s, k0)                                \
    do {                                                 \
        GLD_LDS16(Agb + (k0), &As[s][wl]);               \
        GLD_LDS16(Agb + (k0) + 8 * K, &As[s][wl + 512]); \
    } while (0)

    f32x4 g0, g1, g2, g3;  // in-flight A f32 (AF32 path)
#define ALOAD(k0)                            \
    do {                                     \
        g0 = *(const f32x4*)(Agf + (k0));    \
        g1 = *(const f32x4*)(Agf + (k0) + 4);\
        g2 = *(const f32x4*)(Agf + (k0) + 8);\
        g3 = *(const f32x4*)(Agf + (k0) + 12);\
    } while (0)
#define AWRITE(s)                                      \
    do {                                               \
        u32x4 lo, hi;                                  \
        lo.x = cvtpk_bf16_ns(g0[0], g0[1]);            \
        lo.y = cvtpk_bf16_ns(g0[2], g0[3]);            \
        lo.z = cvtpk_bf16_ns(g1[0], g1[1]);            \
        lo.w = cvtpk_bf16_ns(g1[2], g1[3]);            \
        hi.x = cvtpk_bf16_ns(g2[0], g2[1]);            \
        hi.y = cvtpk_bf16_ns(g2[2], g2[3]);            \
        hi.z = cvtpk_bf16_ns(g3[0], g3[1]);            \
        hi.w = cvtpk_bf16_ns(g3[2], g3[3]);            \
        *(u32x4*)&As[s][wbase + wslot0] = lo;          \
        *(u32x4*)&As[s][wbase + wslot1] = hi;          \
    } while (0)

    f32x4 acc[4][2];
#pragma unroll
    for (int i = 0; i < 4; i++)
#pragma unroll
        for (int j = 0; j < 2; j++) {
            f32x4 z = {0.f, 0.f, 0.f, 0.f};
            acc[i][j] = z;
        }

    // prologue: tile 0
    BSTAGE(0, 0);
    if (AF32) {
        ALOAD(0);
        AWRITE(0);
    } else {
        ASTAGE_DMA(0, 0);
    }

    for (int k0 = 0; k0 < K; k0 += 64) {
        const int s = (k0 >> 6) & 1;
        // barrier: drains tile-t staging (B DMA via per-wave vmcnt, A ds_write via
        // lgkm) and fences iter t-1's reads of stage s^1 before its overwrite.
        __syncthreads();
        const bool more = (k0 + 64) < K;
        if (more) {
            BSTAGE(s ^ 1, k0 + 64);
            if (AF32) ALOAD(k0 + 64);  // latency hides under the MFMA phase below
            else ASTAGE_DMA(s ^ 1, k0 + 64);
        }

        short8 a0[4], a1[4], b0[2], b1[2];
#pragma unroll
        for (int mt = 0; mt < 4; mt++) {
            const int row = (wm + mt * 16 + l15) * 64;
            a0[mt] = *(const short8*)&As[s][row + ((quad ^ sx) << 3)];
            a1[mt] = *(const short8*)&As[s][row + (((4 | quad) ^ sx) << 3)];
        }
#pragma unroll
        for (int nt = 0; nt < 2; nt++) {
            const int row = (wn + nt * 16 + l15) * 64;
            b0[nt] = *(const short8*)&Bs[s][row + ((quad ^ sx) << 3)];
            b1[nt] = *(const short8*)&Bs[s][row + (((4 | quad) ^ sx) << 3)];
        }
#pragma unroll
        for (int mt = 0; mt < 4; mt++)
#pragma unroll
            for (int nt = 0; nt < 2; nt++) acc[mt][nt] = MFMA16(a0[mt], b0[nt], acc[mt][nt]);
#pragma unroll
        for (int mt = 0; mt < 4; mt++)
#pragma unroll
            for (int nt = 0; nt < 2; nt++) acc[mt][nt] = MFMA16(a1[mt], b1[nt], acc[mt][nt]);

        if (AF32 && more) AWRITE(s ^ 1);  // vmcnt wait inserted by compiler before cvt
    }
#undef BSTAGE
#undef ASTAGE_DMA
#undef ALOAD
#undef AWRITE

    float bv[2];
#pragma unroll
    for (int nt = 0; nt < 2; nt++) bv[nt] = bias[n0 + wn + nt * 16 + l15];

#pragma unroll
    for (int mt = 0; mt < 4; mt++)
#pragma unroll
        for (int nt = 0; nt < 2; nt++)
#pragma unroll
            for (int i = 0; i < 4; i++) {
                int m = m0 + wm + mt * 16 + quad * 4 + i;
                int n = n0 + wn + nt * 16 + l15;
                float val = acc[mt][nt][i] + bv[nt];
                if (MODE == 0) {
                    int bb = m >> 11, ns = m & 2047, h = n >> 6, c = n & 63;
                    ((unsigned short*)Cv)[(size_t)(bb * 16 + h) * 131072 + (size_t)ns * 64 + c] =
                        f2bf(val);
                } else {
                    ((float*)Cv)[(size_t)m * N + n] = val;
                }
            }
}

// ---------- fallback GEMM (f32 operands, inline convert, LDS-staged) ----------
template <bool AF32, bool BF32, int MODE>
__global__ __launch_bounds__(256) void gemm_bias_kernel(
    const void* __restrict__ Av, const void* __restrict__ Bv,
    const float* __restrict__ bias, void* __restrict__ Cv, int M, int N, int K) {
    __shared__ __align__(16) unsigned short As[128][40];
    __shared__ __align__(16) unsigned short Bs[128][40];

    const int tid = threadIdx.x;
    const int wave = tid >> 6, lane = tid & 63;
    const int l15 = lane & 15, quad = lane >> 4;
    const int m0 = blockIdx.x * 128, n0 = blockIdx.y * 128;
    const int wm = (wave >> 1) * 64, wn = (wave & 1) * 64;

    f32x4 acc[4][4];
#pragma unroll
    for (int i = 0; i < 4; i++)
#pragma unroll
        for (int j = 0; j < 4; j++) {
            f32x4 z = {0.f, 0.f, 0.f, 0.f};
            acc[i][j] = z;
        }

    for (int k0 = 0; k0 < K; k0 += 32) {
        __syncthreads();
#pragma unroll
        for (int rep = 0; rep < 2; rep++) {
            int chunk = tid + rep * 256;
            int row = chunk >> 2, c8 = (chunk & 3) * 8;
            if (AF32) {
                const float* Af = (const float*)Av;
                *(u32x4*)&As[row][c8] = cvt8(&Af[(size_t)(m0 + row) * K + k0 + c8]);
            } else {
                const unsigned short* Ab = (const unsigned short*)Av;
                *(f32x4*)&As[row][c8] = *(const f32x4*)&Ab[(size_t)(m0 + row) * K + k0 + c8];
            }
            if (BF32) {
                const float* Bf = (const float*)Bv;
                *(u32x4*)&Bs[row][c8] = cvt8(&Bf[(size_t)(n0 + row) * K + k0 + c8]);
            } else {
                const unsigned short* Bb = (const unsigned short*)Bv;
                *(f32x4*)&Bs[row][c8] = *(const f32x4*)&Bb[(size_t)(n0 + row) * K + k0 + c8];
            }
        }
        __syncthreads();

        short8 a[4], b[4];
#pragma unroll
        for (int mt = 0; mt < 4; mt++) a[mt] = *(const short8*)&As[wm + mt * 16 + l15][quad * 8];
#pragma unroll
        for (int nt = 0; nt < 4; nt++) b[nt] = *(const short8*)&Bs[wn + nt * 16 + l15][quad * 8];
#pragma unroll
        for (int mt = 0; mt < 4; mt++)
#pragma unroll
            for (int nt = 0; nt < 4; nt++) acc[mt][nt] = MFMA16(a[mt], b[nt], acc[mt][nt]);
    }

    float bv[4];
#pragma unroll
    for (int nt = 0; nt < 4; nt++) bv[nt] = bias[n0 + wn + nt * 16 + l15];

#pragma unroll
    for (int mt = 0; mt < 4; mt++)
#pragma unroll
        for (int nt = 0; nt < 4; nt++)
#pragma unroll
            for (int i = 0; i < 4; i++) {
                int m = m0 + wm + mt * 16 + quad * 4 + i;
                int n = n0 + wn + nt * 16 + l15;
                float val = acc[mt][nt][i] + bv[nt];
                if (MODE == 0) {
                    int bb = m >> 11, ns = m & 2047, h = n >> 6, c = n & 63;
                    ((unsigned short*)Cv)[(size_t)(bb * 16 + h) * 131072 + (size_t)ns * 64 + c] =
                        f2bf(val);
                } else {
                    ((float*)Cv)[(size_t)m * N + n] = val;
                }
            }
}

// V [bh][2048][64] bf16 -> Vt [bh][64][2048] bf16.  64x64 tiles via LDS.
__global__ __launch_bounds__(256) void transpose_kernel(const unsigned short* __restrict__ V,
                                                        unsigned short* __restrict__ Vt) {
    __shared__ __align__(16) unsigned short T[64][72];
    const int tid = threadIdx.x;
    const int n0 = blockIdx.x * 64;
    const size_t base = (size_t)blockIdx.y * 131072;
#pragma unroll
    for (int rep = 0; rep < 2; rep++) {
        int chunk = tid + rep * 256;
        int row = chunk >> 3, c8 = (chunk & 7) * 8;
        *(short8*)&T[row][c8] = *(const short8*)&V[base + (size_t)(n0 + row) * 64 + c8];
    }
    __syncthreads();
#pragma unroll
    for (int rep = 0; rep < 2; rep++) {
        int chunk = tid + rep * 256;
        int d = chunk >> 3, n8 = (chunk & 7) * 8;
        short8 o;
#pragma unroll
        for (int j = 0; j < 8; j++) o[j] = (short)T[n8 + j][d];
        *(short8*)&Vt[base + (size_t)d * 2048 + n0 + n8] = o;
    }
}

// Flash attention — EXACT round-5 configuration (80.1us r5, 78.9-80.5us r10/r11,
// 0 bank conflicts). In-register P via permlane regroup; K+V^T double-buffered
// in 32KB, one barrier per iter; Q global->reg; row-sum on the matrix pipe.
__global__ __launch_bounds__(256, 4) void attn_kernel(const unsigned short* __restrict__ V,
                                                      const unsigned short* __restrict__ Vt,
                                                      unsigned short* __restrict__ O) {
    __shared__ __align__(16) unsigned short Ks[2][64 * 64];   // kv rows x dh, swizzled (dbuf)
    __shared__ __align__(16) unsigned short VTs[2][64 * 64];  // dh rows x kv, swizzled (dbuf)

    const int tid = threadIdx.x;
    const int wave = tid >> 6, lane = tid & 63;
    const int l15 = lane & 15, quad = lane >> 4;
    const int sx = l15 & 7;  // row&7 for all fragment rows (row = base16*k + l15)

    // XCD-aware remap: dispatch ids round-robin XCDs; each XCD gets a contiguous
    // 8-head group (4MB K/V working set = one L2). Bijective.
    const int flat = blockIdx.y * 16 + blockIdx.x;
    const int bh = (flat & 7) * 8 + ((flat >> 3) & 7);
    const int q0 = (flat >> 6) * 128;

    const unsigned short* Vh = V + (size_t)bh * 131072;
    const unsigned short* VhT = Vt + (size_t)bh * 131072;
    const int wm = wave * 32;

    // DMA source: lane's LDS row-within-instr = lane>>3, 16B slot = lane&7; global
    // column slot pre-swizzled (lane&7)^(row&7), row&7 == lane>>3.
    const int srow = wave * 16 + (lane >> 3);
    const int scol = ((lane & 7) ^ (lane >> 3)) * 8;
    const unsigned short* gK = Vh + (size_t)srow * 64 + scol;
    const unsigned short* gVT = VhT + (size_t)srow * 2048 + scol;

#define KSTAGE(s, kv)                                                       \
    do {                                                                    \
        GLD_LDS16(gK + (size_t)(kv) * 64, &Ks[s][wave * 1024]);             \
        GLD_LDS16(gK + (size_t)(kv) * 64 + 512, &Ks[s][wave * 1024 + 512]); \
    } while (0)
#define VSTAGE(s, kv)                                                 \
    do {                                                              \
        GLD_LDS16(gVT + (kv), &VTs[s][wave * 1024]);                  \
        GLD_LDS16(gVT + (kv) + 8 * 2048, &VTs[s][wave * 1024 + 512]); \
    } while (0)

    KSTAGE(0, 0);  // prologue DMAs overlap the Q register loads below
    VSTAGE(0, 0);

    // Q fragments straight from global; scale = 0.125 * log2(e) folded in-register.
    short8 bq[2][2];
#pragma unroll
    for (int mt = 0; mt < 2; mt++)
#pragma unroll
        for (int ks = 0; ks < 2; ks++) {
            short8 g = *(const short8*)&Vh[(size_t)(q0 + wm + mt * 16 + l15) * 64 + ks * 32 +
                                           quad * 8];
            u32x4 a;
            a.x = cvtpk_bf16(bf2f((unsigned short)g[0]) * 0.1803368801f,
                             bf2f((unsigned short)g[1]) * 0.1803368801f);
            a.y = cvtpk_bf16(bf2f((unsigned short)g[2]) * 0.1803368801f,
                             bf2f((unsigned short)g[3]) * 0.1803368801f);
            a.z = cvtpk_bf16(bf2f((unsigned short)g[4]) * 0.1803368801f,
                             bf2f((unsigned short)g[5]) * 0.1803368801f);
            a.w = cvtpk_bf16(bf2f((unsigned short)g[6]) * 0.1803368801f,
                             bf2f((unsigned short)g[7]) * 0.1803368801f);
            bq[mt][ks] = *(short8*)&a;
        }

    // B-fragment of bf16 ones for the row-sum MFMA
    short8 vones;
#pragma unroll
    for (int j = 0; j < 8; j++) vones[j] = (short)0x3F80;

    f32x4 oacc[2][4];
    f32x4 lsacc[2];
#pragma unroll
    for (int mt = 0; mt < 2; mt++) {
        f32x4 z = {0.f, 0.f, 0.f, 0.f};
        lsacc[mt] = z;
#pragma unroll
        for (int ct = 0; ct < 4; ct++) oacc[mt][ct] = z;
    }

    for (int kv0 = 0; kv0 < 2048; kv0 += 64) {
        const int s = (kv0 >> 6) & 1;
        // ONE barrier per iter: drains stage-s DMA (issued right after barrier(t-1),
        // a full iteration in flight) and fences iter t-1's reads of stage s^1
        // before the STAGE below overwrites it.
        __syncthreads();
        if (kv0 + 64 < 2048) {
            KSTAGE(s ^ 1, kv0 + 64);
            VSTAGE(s ^ 1, kv0 + 64);
        }

        f32x4 st[4][2];
#pragma unroll
        for (int nt = 0; nt < 4; nt++) {
            const int krow = (nt * 16 + l15) * 64;
            short8 ak0 = *(const short8*)&Ks[s][krow + ((quad ^ sx) << 3)];
            short8 ak1 = *(const short8*)&Ks[s][krow + (((4 | quad) ^ sx) << 3)];
#pragma unroll
            for (int mt = 0; mt < 2; mt++) {
                f32x4 z = {0.f, 0.f, 0.f, 0.f};
                z = MFMA16(ak0, bq[mt][0], z);
                z = MFMA16(ak1, bq[mt][1], z);
                st[nt][mt] = z;
            }
        }

        // softmax fully in-register: exp -> pack pairs -> quad regroup via permlane
        short8 ap[2][2];
#pragma unroll
        for (int mt = 0; mt < 2; mt++) {
            unsigned int w[4][2];
#pragma unroll
            for (int nt = 0; nt < 4; nt++) {
                f32x4 p;
#pragma unroll
                for (int i = 0; i < 4; i++) p[i] = FAST_EXP2(st[nt][mt][i]);
                w[nt][0] = cvtpk_bf16(p[0], p[1]);
                w[nt][1] = cvtpk_bf16(p[2], p[3]);
            }
#pragma unroll
            for (int kt = 0; kt < 2; kt++) {
                unsigned int x0 = w[2 * kt][0], x1 = w[2 * kt][1];
                unsigned int y0 = w[2 * kt + 1][0], y1 = w[2 * kt + 1][1];
                permlane_regroup(x0, y0);
                permlane_regroup(x1, y1);
                u32x4 a;
                a.x = x0;  // j=0,1
                a.y = x1;  // j=2,3
                a.z = y0;  // j=4,5
                a.w = y1;  // j=6,7
                ap[mt][kt] = *(short8*)&a;
            }
        }

#pragma unroll
        for (int kt = 0; kt < 2; kt++) {
#pragma unroll
            for (int ct = 0; ct < 4; ct++) {
                short8 bvf =
                    *(const short8*)&VTs[s][(ct * 16 + l15) * 64 + ((((kt << 2) | quad) ^ sx) << 3)];
#pragma unroll
                for (int mt = 0; mt < 2; mt++) oacc[mt][ct] = MFMA16(ap[mt][kt], bvf, oacc[mt][ct]);
            }
            // row-sum on the matrix pipe: lsacc[mt] row q=quad*4+i accumulates sum_kv P.
#pragma unroll
            for (int mt = 0; mt < 2; mt++) lsacc[mt] = MFMA16(ap[mt][kt], vones, lsacc[mt]);
        }
    }
#undef KSTAGE
#undef VSTAGE

    float inv[2][4];
#pragma unroll
    for (int mt = 0; mt < 2; mt++)
#pragma unroll
        for (int i = 0; i < 4; i++) inv[mt][i] = 1.0f / lsacc[mt][i];

    const int bb = bh >> 4, h = bh & 15;
#pragma unroll
    for (int mt = 0; mt < 2; mt++)
#pragma unroll
        for (int i = 0; i < 4; i++) {
            int m = q0 + wm + mt * 16 + quad * 4 + i;
            size_t rowbase = ((size_t)(bb * 2048 + m)) * 1024 + h * 64;
#pragma unroll
            for (int ct = 0; ct < 4; ct++)
                O[rowbase + ct * 16 + l15] = f2bf(oacc[mt][ct][i] * inv[mt][i]);
        }
}

extern "C" void kernel_launch(void* const* d_in, const int* in_sizes, int n_in, void* d_out,
                              int out_size, void* d_ws, size_t ws_size, hipStream_t stream) {
    (void)in_sizes; (void)n_in; (void)out_size;
    const float* x = (const float*)d_in[0];    // [4,2048,1024] f32
    const float* v_w = (const float*)d_in[1];  // [1024,1024] (out,in)
    const float* v_b = (const float*)d_in[2];  // [1024]
    const float* o_w = (const float*)d_in[3];  // [1024,1024]
    const float* o_b = (const float*)d_in[4];  // [1024]
    float* out = (float*)d_out;                // [8192,1024] f32 = 32 MB

    unsigned short* Vbuf = (unsigned short*)d_out;       // V bf16 (16 MB)
    unsigned short* Vtbuf = Vbuf + (size_t)8192 * 1024;  // Vt bf16 (16 MB)
    unsigned short* Obuf = (unsigned short*)d_ws;        // 16.78 MB (proven OK)

    const size_t need =
        ((size_t)8192 * 1024 /*Obuf*/ + (size_t)8192 * 1024 /*x spare*/ + 2 * (size_t)1024 * 1024) * 2;
    if (ws_size >= need) {
        unsigned short* xbf = Obuf + (size_t)8192 * 1024;  // spare (x-cvt now fused)
        unsigned short* wv = xbf + (size_t)8192 * 1024;
        unsigned short* wo = wv + (size_t)1024 * 1024;
        cvt2_kernel<<<1024, 256, 0, stream>>>(v_w, wv, o_w, wo, 131072);
        gemm_dma_kernel<true, 0>
            <<<dim3(64, 8), 512, 0, stream>>>(x, wv, v_b, Vbuf, 8192, 1024, 1024);
        transpose_kernel<<<dim3(32, 64), 256, 0, stream>>>(Vbuf, Vtbuf);
        attn_kernel<<<dim3(16, 64), 256, 0, stream>>>(Vbuf, Vtbuf, Obuf);
        gemm_dma_kernel<false, 1>
            <<<dim3(64, 8), 512, 0, stream>>>(Obuf, wo, o_b, out, 8192, 1024, 1024);
    } else {
        gemm_bias_kernel<true, true, 0>
            <<<dim3(64, 8), 256, 0, stream>>>(x, v_w, v_b, Vbuf, 8192, 1024, 1024);
        transpose_kernel<<<dim3(32, 64), 256, 0, stream>>>(Vbuf, Vtbuf);
        attn_kernel<<<dim3(16, 64), 256, 0, stream>>>(Vbuf, Vtbuf, Obuf);
        gemm_bias_kernel<false, true, 1>
            <<<dim3(64, 8), 256, 0, stream>>>(Obuf, o_w, o_b, out, 8192, 1024, 1024);
    }
}

// Round 13
// 205.342 us; speedup vs baseline: 1.0667x; 1.0667x over previous
//
#include <hip/hip_runtime.h>
#include <stdint.h>

typedef __attribute__((ext_vector_type(8))) short short8;
typedef __attribute__((ext_vector_type(4))) float f32x4;
typedef __attribute__((ext_vector_type(4))) unsigned int u32x4;
typedef __attribute__((ext_vector_type(2))) unsigned int u32x2;

#define MFMA16(a, b, c) __builtin_amdgcn_mfma_f32_16x16x32_bf16((a), (b), (c), 0, 0, 0)

// async global->LDS DMA, 16B per lane; LDS dest = wave-uniform base + lane*16
#define GLD_LDS16(g, l)                                                                  \
    __builtin_amdgcn_global_load_lds((const __attribute__((address_space(1))) void*)(g), \
                                     (__attribute__((address_space(3))) void*)(l), 16, 0, 0)

// single-instruction v_exp_f32 (exp2f without -ffast-math is a slow libm call)
#if defined(__has_builtin)
#if __has_builtin(__builtin_amdgcn_exp2f)
#define FAST_EXP2(x) __builtin_amdgcn_exp2f(x)
#endif
#endif
#ifndef FAST_EXP2
__device__ __forceinline__ float fast_exp2_asm(float x) {
    float r;
    asm volatile("v_exp_f32 %0, %1\ns_nop 1" : "=v"(r) : "v"(x));
    return r;
}
#define FAST_EXP2(x) fast_exp2_asm(x)
#endif

#if defined(__has_builtin)
#if __has_builtin(__builtin_amdgcn_permlane32_swap) && __has_builtin(__builtin_amdgcn_permlane16_swap)
#define HAVE_PERMLANE_SWAP 1
#endif
#endif

// Regroup a pair of packed-u32 registers across quads:
//   in : x = [X0,X1,X2,X3], y = [Y0,Y1,Y2,Y3]   (quad-rows of 16 lanes)
//   out: x = [X0,X2,Y0,Y2], y = [X1,X3,Y1,Y3]
// via permlane32_swap then permlane16_swap. Builtin path lets the compiler insert
// the cross-lane hazard wait-states (raw asm was the round-4 nondeterminism bug);
// fallback asm carries generous s_nop padding for the same reason.
__device__ __forceinline__ void permlane_regroup(unsigned int& x, unsigned int& y) {
#ifdef HAVE_PERMLANE_SWAP
    {
        auto r = __builtin_amdgcn_permlane32_swap(x, y, false, false);
        auto r2 = __builtin_amdgcn_permlane16_swap(r[0], r[1], false, false);
        x = r2[0];
        y = r2[1];
    }
#else
    asm volatile(
        "s_nop 3\n\t"
        "v_permlane32_swap_b32 %0, %1\n\t"
        "s_nop 3\n\t"
        "v_permlane16_swap_b32 %0, %1\n\t"
        "s_nop 3"
        : "+v"(x), "+v"(y));
#endif
}

__device__ __forceinline__ float bf2f(unsigned short u) {
    unsigned int x = ((unsigned int)u) << 16;
    float f;
    __builtin_memcpy(&f, &x, 4);
    return f;
}
__device__ __forceinline__ unsigned short f2bf(float f) {  // RNE
    unsigned int x;
    __builtin_memcpy(&x, &f, 4);
    unsigned int r = x + 0x7FFFu + ((x >> 16) & 1u);
    return (unsigned short)(r >> 16);
}
// pack two f32 -> two bf16 (round-half-up) in one u32
__device__ __forceinline__ unsigned int pack2bf(float a, float b) {
    unsigned int ua, ub;
    __builtin_memcpy(&ua, &a, 4);
    __builtin_memcpy(&ub, &b, 4);
    return __builtin_amdgcn_perm(ub + 0x8000u, ua + 0x8000u, 0x07060302u);
}
// single-instruction pack: lo = bf16(a), hi = bf16(b), RNE.
// Trailing s_nop covers the VALU-write -> cross-lane-read hazard when the result
// feeds a permlane (compiler cannot see inside this asm to insert wait-states).
__device__ __forceinline__ unsigned int cvtpk_bf16(float a, float b) {
    unsigned int r;
    asm("v_cvt_pk_bf16_f32 %0, %1, %2\n\ts_nop 1" : "=v"(r) : "v"(a), "v"(b));
    return r;
}
// no-s_nop variant: result feeds MEMORY (ds_write), not a cross-lane op
__device__ __forceinline__ unsigned int cvtpk_bf16_ns(float a, float b) {
    unsigned int r;
    asm("v_cvt_pk_bf16_f32 %0, %1, %2" : "=v"(r) : "v"(a), "v"(b));
    return r;
}
__device__ __forceinline__ u32x4 cvt8(const float* p) {
    f32x4 g0 = *(const f32x4*)p;
    f32x4 g1 = *(const f32x4*)(p + 4);
    u32x4 r;
    r.x = pack2bf(g0[0], g0[1]);
    r.y = pack2bf(g0[2], g0[3]);
    r.z = pack2bf(g1[0], g1[1]);
    r.w = pack2bf(g1[2], g1[3]);
    return r;
}

// fused elementwise f32 -> bf16 for x, v_w, o_w in ONE launch (x8 per thread)
__global__ __launch_bounds__(256) void cvt3_kernel(const float* __restrict__ a,
                                                   unsigned short* __restrict__ oa, int na8,
                                                   const float* __restrict__ b,
                                                   unsigned short* __restrict__ ob, int nb8,
                                                   const float* __restrict__ c,
                                                   unsigned short* __restrict__ oc, int nc8) {
    int i = blockIdx.x * 256 + threadIdx.x;
    if (i < na8) {
        *(u32x4*)(oa + (size_t)i * 8) = cvt8(a + (size_t)i * 8);
    } else if (i < na8 + nb8) {
        int j = i - na8;
        *(u32x4*)(ob + (size_t)j * 8) = cvt8(b + (size_t)j * 8);
    } else if (i < na8 + nb8 + nc8) {
        int j = i - na8 - nb8;
        *(u32x4*)(oc + (size_t)j * 8) = cvt8(c + (size_t)j * 8);
    }
}

// ---------- main-path GEMM: r11 config (proven 211us total) + fused V-transpose ----------
// BM=BN=128, BK=64, 8 waves (512 thr), dbuf global_load_lds, conflict-free swizzled LDS.
// C = A @ B^T + bias; A [M,K] bf16, B [N,K] bf16.
// MODE 0: writes V (bf16 head-major scatter) AND Vt (bf16 [bh][64][2048]) — the block's
//   128x128 C-tile is exactly one [2 heads][64][128] Vt tile; after the K-loop the 64KB
//   LDS is dead, so: barrier -> packed-bf16 into T[128][136] (pad 136: 16B-aligned rows,
//   read conflict-free, write <=4-way) -> barrier -> coalesced 256B Vt row writes.
//   This deletes the separate transpose kernel (16MB read + 16MB write + a launch).
// MODE 1: C f32 row-major (unchanged r11 epilogue).
template <int MODE>
__global__ __launch_bounds__(512, 4) void gemm_dma_kernel(
    const unsigned short* __restrict__ A, const unsigned short* __restrict__ B,
    const float* __restrict__ bias, void* __restrict__ Cv, unsigned short* __restrict__ Vt,
    int M, int N, int K) {
    // flat 64KB: As = [0,16384), Bs = [16384,32768); reused post-loop as T[128][136]
    __shared__ __align__(16) unsigned short SMEM[32768];

    const int tid = threadIdx.x;
    const int wave = tid >> 6, lane = tid & 63;  // wave 0..7
    const int l15 = lane & 15, quad = lane >> 4;
    const int sx = l15 & 7;  // row&7 for fragment rows (row = base16*k + l15)
    // XCD remap: id round-robins XCDs; each XCD owns 8 contiguous m-tiles, n fastest.
    const int id = blockIdx.y * gridDim.x + blockIdx.x;  // dispatch-linear
    const int xcd = id & 7;
    const int p = id >> 3;
    const int m0 = (xcd * 8 + (p >> 3)) * 128, n0 = (p & 7) * 128;
    const int wm = (wave >> 2) * 64, wn = (wave & 3) * 32;  // 2x4 wave grid, 64x32 each

    // DMA source: wave stages 16 rows (2 instrs x 8 rows of 128B) of A and of B.
    // lane's row-within-instr = lane>>3 (== row&7), 16B col slot = (lane&7)^(lane>>3).
    const int srow = wave * 16 + (lane >> 3);
    const int scol = ((lane & 7) ^ (lane >> 3)) * 8;
    const unsigned short* Ag = A + (size_t)(m0 + srow) * K + scol;
    const unsigned short* Bg = B + (size_t)(n0 + srow) * K + scol;
    const int wl = wave * 1024;  // 16 rows x 64 shorts; lane*16B appended by HW

#define STAGE(s, k0)                                                    \
    do {                                                                \
        GLD_LDS16(Ag + (k0), &SMEM[(s)*8192 + wl]);                     \
        GLD_LDS16(Ag + (k0) + 8 * K, &SMEM[(s)*8192 + wl + 512]);       \
        GLD_LDS16(Bg + (k0), &SMEM[16384 + (s)*8192 + wl]);             \
        GLD_LDS16(Bg + (k0) + 8 * K, &SMEM[16384 + (s)*8192 + wl + 512]); \
    } while (0)

    f32x4 acc[4][2];
#pragma unroll
    for (int i = 0; i < 4; i++)
#pragma unroll
        for (int j = 0; j < 2; j++) {
            f32x4 z = {0.f, 0.f, 0.f, 0.f};
            acc[i][j] = z;
        }

    STAGE(0, 0);  // prologue
    for (int k0 = 0; k0 < K; k0 += 64) {
        const int s = (k0 >> 6) & 1;
        __syncthreads();
        if (k0 + 64 < K) STAGE(s ^ 1, k0 + 64);

        short8 a0[4], a1[4], b0[2], b1[2];
#pragma unroll
        for (int mt = 0; mt < 4; mt++) {
            const int row = s * 8192 + (wm + mt * 16 + l15) * 64;
            a0[mt] = *(const short8*)&SMEM[row + ((quad ^ sx) << 3)];
            a1[mt] = *(const short8*)&SMEM[row + (((4 | quad) ^ sx) << 3)];
        }
#pragma unroll
        for (int nt = 0; nt < 2; nt++) {
            const int row = 16384 + s * 8192 + (wn + nt * 16 + l15) * 64;
            b0[nt] = *(const short8*)&SMEM[row + ((quad ^ sx) << 3)];
            b1[nt] = *(const short8*)&SMEM[row + (((4 | quad) ^ sx) << 3)];
        }
#pragma unroll
        for (int mt = 0; mt < 4; mt++)
#pragma unroll
            for (int nt = 0; nt < 2; nt++) acc[mt][nt] = MFMA16(a0[mt], b0[nt], acc[mt][nt]);
#pragma unroll
        for (int mt = 0; mt < 4; mt++)
#pragma unroll
            for (int nt = 0; nt < 2; nt++) acc[mt][nt] = MFMA16(a1[mt], b1[nt], acc[mt][nt]);
    }
#undef STAGE

    float bv[2];
#pragma unroll
    for (int nt = 0; nt < 2; nt++) bv[nt] = bias[n0 + wn + nt * 16 + l15];

    if (MODE == 1) {
#pragma unroll
        for (int mt = 0; mt < 4; mt++)
#pragma unroll
            for (int nt = 0; nt < 2; nt++)
#pragma unroll
                for (int i = 0; i < 4; i++) {
                    int m = m0 + wm + mt * 16 + quad * 4 + i;
                    int n = n0 + wn + nt * 16 + l15;
                    ((float*)Cv)[(size_t)m * N + n] = acc[mt][nt][i] + bv[nt];
                }
        return;
    }

    // MODE 0: V scatter + LDS transpose -> Vt
    __syncthreads();  // all waves done with fragment reads before SMEM reuse as T
#pragma unroll
    for (int mt = 0; mt < 4; mt++)
#pragma unroll
        for (int nt = 0; nt < 2; nt++) {
            const int nl = wn + nt * 16 + l15;
            const int n = n0 + nl;
            const int bh = ((m0 >> 11) * 16) + (n >> 6);
            const int c = n & 63;
#pragma unroll
            for (int i = 0; i < 4; i += 2) {
                const int ml = wm + mt * 16 + quad * 4 + i;
                const int m = m0 + ml;
                float v0 = acc[mt][nt][i] + bv[nt];
                float v1 = acc[mt][nt][i + 1] + bv[nt];
                // V head-major scatter (as r11)
                ((unsigned short*)Cv)[(size_t)bh * 131072 + (size_t)(m & 2047) * 64 + c] =
                    f2bf(v0);
                ((unsigned short*)Cv)[(size_t)bh * 131072 + (size_t)((m + 1) & 2047) * 64 + c] =
                    f2bf(v1);
                // T[n_local][m_local..m_local+1] packed (ml even: quad*4+i, i even)
                *(unsigned int*)&SMEM[nl * 136 + ml] = cvtpk_bf16_ns(v0, v1);
            }
        }
    __syncthreads();

    // coalesced Vt writes: 2048 short8 chunks over 512 threads
    const int bb2 = m0 >> 11, ns0 = m0 & 2047, h0 = n0 >> 6;
#pragma unroll
    for (int r = 0; r < 4; r++) {
        int cidx = tid + r * 512;       // 0..2047
        int hs = cidx >> 10;            // head select 0..1
        int crow = (cidx >> 4) & 63;    // d index 0..63
        int seg = cidx & 15;            // 8-short segment of the 128-token row
        short8 vrow = *(const short8*)&SMEM[(hs * 64 + crow) * 136 + seg * 8];
        *(short8*)&Vt[(size_t)(bb2 * 16 + h0 + hs) * 131072 + (size_t)crow * 2048 + ns0 +
                      seg * 8] = vrow;
    }
}

// ---------- fallback GEMM (f32 operands, inline convert, LDS-staged) ----------
template <bool AF32, bool BF32, int MODE>
__global__ __launch_bounds__(256) void gemm_bias_kernel(
    const void* __restrict__ Av, const void* __restrict__ Bv,
    const float* __restrict__ bias, void* __restrict__ Cv, int M, int N, int K) {
    __shared__ __align__(16) unsigned short As[128][40];
    __shared__ __align__(16) unsigned short Bs[128][40];

    const int tid = threadIdx.x;
    const int wave = tid >> 6, lane = tid & 63;
    const int l15 = lane & 15, quad = lane >> 4;
    const int m0 = blockIdx.x * 128, n0 = blockIdx.y * 128;
    const int wm = (wave >> 1) * 64, wn = (wave & 1) * 64;

    f32x4 acc[4][4];
#pragma unroll
    for (int i = 0; i < 4; i++)
#pragma unroll
        for (int j = 0; j < 4; j++) {
            f32x4 z = {0.f, 0.f, 0.f, 0.f};
            acc[i][j] = z;
        }

    for (int k0 = 0; k0 < K; k0 += 32) {
        __syncthreads();
#pragma unroll
        for (int rep = 0; rep < 2; rep++) {
            int chunk = tid + rep * 256;
            int row = chunk >> 2, c8 = (chunk & 3) * 8;
            if (AF32) {
                const float* Af = (const float*)Av;
                *(u32x4*)&As[row][c8] = cvt8(&Af[(size_t)(m0 + row) * K + k0 + c8]);
            } else {
                const unsigned short* Ab = (const unsigned short*)Av;
                *(f32x4*)&As[row][c8] = *(const f32x4*)&Ab[(size_t)(m0 + row) * K + k0 + c8];
            }
            if (BF32) {
                const float* Bf = (const float*)Bv;
                *(u32x4*)&Bs[row][c8] = cvt8(&Bf[(size_t)(n0 + row) * K + k0 + c8]);
            } else {
                const unsigned short* Bb = (const unsigned short*)Bv;
                *(f32x4*)&Bs[row][c8] = *(const f32x4*)&Bb[(size_t)(n0 + row) * K + k0 + c8];
            }
        }
        __syncthreads();

        short8 a[4], b[4];
#pragma unroll
        for (int mt = 0; mt < 4; mt++) a[mt] = *(const short8*)&As[wm + mt * 16 + l15][quad * 8];
#pragma unroll
        for (int nt = 0; nt < 4; nt++) b[nt] = *(const short8*)&Bs[wn + nt * 16 + l15][quad * 8];
#pragma unroll
        for (int mt = 0; mt < 4; mt++)
#pragma unroll
            for (int nt = 0; nt < 4; nt++) acc[mt][nt] = MFMA16(a[mt], b[nt], acc[mt][nt]);
    }

    float bv[4];
#pragma unroll
    for (int nt = 0; nt < 4; nt++) bv[nt] = bias[n0 + wn + nt * 16 + l15];

#pragma unroll
    for (int mt = 0; mt < 4; mt++)
#pragma unroll
        for (int nt = 0; nt < 4; nt++)
#pragma unroll
            for (int i = 0; i < 4; i++) {
                int m = m0 + wm + mt * 16 + quad * 4 + i;
                int n = n0 + wn + nt * 16 + l15;
                float val = acc[mt][nt][i] + bv[nt];
                if (MODE == 0) {
                    int bb = m >> 11, ns = m & 2047, h = n >> 6, c = n & 63;
                    ((unsigned short*)Cv)[(size_t)(bb * 16 + h) * 131072 + (size_t)ns * 64 + c] =
                        f2bf(val);
                } else {
                    ((float*)Cv)[(size_t)m * N + n] = val;
                }
            }
}

// V [bh][2048][64] bf16 -> Vt [bh][64][2048] bf16.  64x64 tiles via LDS.
// (fallback path only — the main path fuses this into gemm_dma<0>)
__global__ __launch_bounds__(256) void transpose_kernel(const unsigned short* __restrict__ V,
                                                        unsigned short* __restrict__ Vt) {
    __shared__ __align__(16) unsigned short T[64][72];
    const int tid = threadIdx.x;
    const int n0 = blockIdx.x * 64;
    const size_t base = (size_t)blockIdx.y * 131072;
#pragma unroll
    for (int rep = 0; rep < 2; rep++) {
        int chunk = tid + rep * 256;
        int row = chunk >> 3, c8 = (chunk & 7) * 8;
        *(short8*)&T[row][c8] = *(const short8*)&V[base + (size_t)(n0 + row) * 64 + c8];
    }
    __syncthreads();
#pragma unroll
    for (int rep = 0; rep < 2; rep++) {
        int chunk = tid + rep * 256;
        int d = chunk >> 3, n8 = (chunk & 7) * 8;
        short8 o;
#pragma unroll
        for (int j = 0; j < 8; j++) o[j] = (short)T[n8 + j][d];
        *(short8*)&Vt[base + (size_t)d * 2048 + n0 + n8] = o;
    }
}

// Flash attention — EXACT round-5 configuration (80.1us r5, 78.9-80.5us r10-r12,
// 0 bank conflicts). In-register P via permlane regroup; K+V^T double-buffered
// in 32KB, one barrier per iter; Q global->reg; row-sum on the matrix pipe.
__global__ __launch_bounds__(256, 4) void attn_kernel(const unsigned short* __restrict__ V,
                                                      const unsigned short* __restrict__ Vt,
                                                      unsigned short* __restrict__ O) {
    __shared__ __align__(16) unsigned short Ks[2][64 * 64];   // kv rows x dh, swizzled (dbuf)
    __shared__ __align__(16) unsigned short VTs[2][64 * 64];  // dh rows x kv, swizzled (dbuf)

    const int tid = threadIdx.x;
    const int wave = tid >> 6, lane = tid & 63;
    const int l15 = lane & 15, quad = lane >> 4;
    const int sx = l15 & 7;  // row&7 for all fragment rows (row = base16*k + l15)

    // XCD-aware remap: dispatch ids round-robin XCDs; each XCD gets a contiguous
    // 8-head group (4MB K/V working set = one L2). Bijective.
    const int flat = blockIdx.y * 16 + blockIdx.x;
    const int bh = (flat & 7) * 8 + ((flat >> 3) & 7);
    const int q0 = (flat >> 6) * 128;

    const unsigned short* Vh = V + (size_t)bh * 131072;
    const unsigned short* VhT = Vt + (size_t)bh * 131072;
    const int wm = wave * 32;

    // DMA source: lane's LDS row-within-instr = lane>>3, 16B slot = lane&7; global
    // column slot pre-swizzled (lane&7)^(row&7), row&7 == lane>>3.
    const int srow = wave * 16 + (lane >> 3);
    const int scol = ((lane & 7) ^ (lane >> 3)) * 8;
    const unsigned short* gK = Vh + (size_t)srow * 64 + scol;
    const unsigned short* gVT = VhT + (size_t)srow * 2048 + scol;

#define KSTAGE(s, kv)                                                       \
    do {                                                                    \
        GLD_LDS16(gK + (size_t)(kv) * 64, &Ks[s][wave * 1024]);             \
        GLD_LDS16(gK + (size_t)(kv) * 64 + 512, &Ks[s][wave * 1024 + 512]); \
    } while (0)
#define VSTAGE(s, kv)                                                 \
    do {                                                              \
        GLD_LDS16(gVT + (kv), &VTs[s][wave * 1024]);                  \
        GLD_LDS16(gVT + (kv) + 8 * 2048, &VTs[s][wave * 1024 + 512]); \
    } while (0)

    KSTAGE(0, 0);  // prologue DMAs overlap the Q register loads below
    VSTAGE(0, 0);

    // Q fragments straight from global; scale = 0.125 * log2(e) folded in-register.
    short8 bq[2][2];
#pragma unroll
    for (int mt = 0; mt < 2; mt++)
#pragma unroll
        for (int ks = 0; ks < 2; ks++) {
            short8 g = *(const short8*)&Vh[(size_t)(q0 + wm + mt * 16 + l15) * 64 + ks * 32 +
                                           quad * 8];
            u32x4 a;
            a.x = cvtpk_bf16(bf2f((unsigned short)g[0]) * 0.1803368801f,
                             bf2f((unsigned short)g[1]) * 0.1803368801f);
            a.y = cvtpk_bf16(bf2f((unsigned short)g[2]) * 0.1803368801f,
                             bf2f((unsigned short)g[3]) * 0.1803368801f);
            a.z = cvtpk_bf16(bf2f((unsigned short)g[4]) * 0.1803368801f,
                             bf2f((unsigned short)g[5]) * 0.1803368801f);
            a.w = cvtpk_bf16(bf2f((unsigned short)g[6]) * 0.1803368801f,
                             bf2f((unsigned short)g[7]) * 0.1803368801f);
            bq[mt][ks] = *(short8*)&a;
        }

    // B-fragment of bf16 ones for the row-sum MFMA
    short8 vones;
#pragma unroll
    for (int j = 0; j < 8; j++) vones[j] = (short)0x3F80;

    f32x4 oacc[2][4];
    f32x4 lsacc[2];
#pragma unroll
    for (int mt = 0; mt < 2; mt++) {
        f32x4 z = {0.f, 0.f, 0.f, 0.f};
        lsacc[mt] = z;
#pragma unroll
        for (int ct = 0; ct < 4; ct++) oacc[mt][ct] = z;
    }

    for (int kv0 = 0; kv0 < 2048; kv0 += 64) {
        const int s = (kv0 >> 6) & 1;
        // ONE barrier per iter: drains stage-s DMA (issued right after barrier(t-1),
        // a full iteration in flight) and fences iter t-1's reads of stage s^1
        // before the STAGE below overwrites it.
        __syncthreads();
        if (kv0 + 64 < 2048) {
            KSTAGE(s ^ 1, kv0 + 64);
            VSTAGE(s ^ 1, kv0 + 64);
        }

        f32x4 st[4][2];
#pragma unroll
        for (int nt = 0; nt < 4; nt++) {
            const int krow = (nt * 16 + l15) * 64;
            short8 ak0 = *(const short8*)&Ks[s][krow + ((quad ^ sx) << 3)];
            short8 ak1 = *(const short8*)&Ks[s][krow + (((4 | quad) ^ sx) << 3)];
#pragma unroll
            for (int mt = 0; mt < 2; mt++) {
                f32x4 z = {0.f, 0.f, 0.f, 0.f};
                z = MFMA16(ak0, bq[mt][0], z);
                z = MFMA16(ak1, bq[mt][1], z);
                st[nt][mt] = z;
            }
        }

        // softmax fully in-register: exp -> pack pairs -> quad regroup via permlane
        short8 ap[2][2];
#pragma unroll
        for (int mt = 0; mt < 2; mt++) {
            unsigned int w[4][2];
#pragma unroll
            for (int nt = 0; nt < 4; nt++) {
                f32x4 p;
#pragma unroll
                for (int i = 0; i < 4; i++) p[i] = FAST_EXP2(st[nt][mt][i]);
                w[nt][0] = cvtpk_bf16(p[0], p[1]);
                w[nt][1] = cvtpk_bf16(p[2], p[3]);
            }
#pragma unroll
            for (int kt = 0; kt < 2; kt++) {
                unsigned int x0 = w[2 * kt][0], x1 = w[2 * kt][1];
                unsigned int y0 = w[2 * kt + 1][0], y1 = w[2 * kt + 1][1];
                permlane_regroup(x0, y0);
                permlane_regroup(x1, y1);
                u32x4 a;
                a.x = x0;  // j=0,1
                a.y = x1;  // j=2,3
                a.z = y0;  // j=4,5
                a.w = y1;  // j=6,7
                ap[mt][kt] = *(short8*)&a;
            }
        }

#pragma unroll
        for (int kt = 0; kt < 2; kt++) {
#pragma unroll
            for (int ct = 0; ct < 4; ct++) {
                short8 bvf =
                    *(const short8*)&VTs[s][(ct * 16 + l15) * 64 + ((((kt << 2) | quad) ^ sx) << 3)];
#pragma unroll
                for (int mt = 0; mt < 2; mt++) oacc[mt][ct] = MFMA16(ap[mt][kt], bvf, oacc[mt][ct]);
            }
            // row-sum on the matrix pipe: lsacc[mt] row q=quad*4+i accumulates sum_kv P.
#pragma unroll
            for (int mt = 0; mt < 2; mt++) lsacc[mt] = MFMA16(ap[mt][kt], vones, lsacc[mt]);
        }
    }
#undef KSTAGE
#undef VSTAGE

    float inv[2][4];
#pragma unroll
    for (int mt = 0; mt < 2; mt++)
#pragma unroll
        for (int i = 0; i < 4; i++) inv[mt][i] = 1.0f / lsacc[mt][i];

    const int bb = bh >> 4, h = bh & 15;
#pragma unroll
    for (int mt = 0; mt < 2; mt++)
#pragma unroll
        for (int i = 0; i < 4; i++) {
            int m = q0 + wm + mt * 16 + quad * 4 + i;
            size_t rowbase = ((size_t)(bb * 2048 + m)) * 1024 + h * 64;
#pragma unroll
            for (int ct = 0; ct < 4; ct++)
                O[rowbase + ct * 16 + l15] = f2bf(oacc[mt][ct][i] * inv[mt][i]);
        }
}

extern "C" void kernel_launch(void* const* d_in, const int* in_sizes, int n_in, void* d_out,
                              int out_size, void* d_ws, size_t ws_size, hipStream_t stream) {
    (void)in_sizes; (void)n_in; (void)out_size;
    const float* x = (const float*)d_in[0];    // [4,2048,1024] f32
    const float* v_w = (const float*)d_in[1];  // [1024,1024] (out,in)
    const float* v_b = (const float*)d_in[2];  // [1024]
    const float* o_w = (const float*)d_in[3];  // [1024,1024]
    const float* o_b = (const float*)d_in[4];  // [1024]
    float* out = (float*)d_out;                // [8192,1024] f32 = 32 MB

    unsigned short* Vbuf = (unsigned short*)d_out;       // V bf16 (16 MB)
    unsigned short* Vtbuf = Vbuf + (size_t)8192 * 1024;  // Vt bf16 (16 MB)
    unsigned short* Obuf = (unsigned short*)d_ws;        // 16.78 MB (proven OK)

    const size_t need =
        ((size_t)8192 * 1024 /*Obuf*/ + (size_t)8192 * 1024 /*x*/ + 2 * (size_t)1024 * 1024) * 2;
    if (ws_size >= need) {
        unsigned short* xbf = Obuf + (size_t)8192 * 1024;
        unsigned short* wv = xbf + (size_t)8192 * 1024;
        unsigned short* wo = wv + (size_t)1024 * 1024;
        cvt3_kernel<<<5120, 256, 0, stream>>>(x, xbf, 1048576, v_w, wv, 131072, o_w, wo, 131072);
        gemm_dma_kernel<0>
            <<<dim3(64, 8), 512, 0, stream>>>(xbf, wv, v_b, Vbuf, Vtbuf, 8192, 1024, 1024);
        attn_kernel<<<dim3(16, 64), 256, 0, stream>>>(Vbuf, Vtbuf, Obuf);
        gemm_dma_kernel<1>
            <<<dim3(64, 8), 512, 0, stream>>>(Obuf, wo, o_b, out, nullptr, 8192, 1024, 1024);
    } else {
        gemm_bias_kernel<true, true, 0>
            <<<dim3(64, 8), 256, 0, stream>>>(x, v_w, v_b, Vbuf, 8192, 1024, 1024);
        transpose_kernel<<<dim3(32, 64), 256, 0, stream>>>(Vbuf, Vtbuf);
        attn_kernel<<<dim3(16, 64), 256, 0, stream>>>(Vbuf, Vtbuf, Obuf);
        gemm_bias_kernel<false, true, 1>
            <<<dim3(64, 8), 256, 0, stream>>>(Obuf, o_w, o_b, out, 8192, 1024, 1024);
    }
}